// Round 6
// baseline (722.522 us; speedup 1.0000x reference)
//
#include <hip/hip_runtime.h>

// R6: same verified bf16-MFMA dataflow as R5; staging restructured.
//  (1) Prologue kernel converts all weights f32->bf16 ONCE into d_ws in the
//      A-fragment layout wT[n][k] (KPAD=KT*32). Main kernel loads A-frags
//      straight from global (L1/L2-resident) -> no wbuf, no per-block weight
//      staging, ~10 fewer barriers, no A-LDS traffic.
//  (2) Activations in chunk-of-8 layout act[k8][tok][8]: wave B-reads are
//      4x256B contiguous -> zero bank conflicts (row-major strides gave
//      structural 8-way aliasing). Same element mapping -> bit-identical.
//  (3) Bias init hoisted per work-item; softmax normalize merged into wsum.

typedef short sx8 __attribute__((ext_vector_type(8)));
typedef short sx4 __attribute__((ext_vector_type(4)));
typedef float fx4 __attribute__((ext_vector_type(4)));

#define TB   1024
#define NW   16
#define MTOK 160
#define CHH  1280   // halves per k-chunk: 160 tok x 8

// LDS byte offsets (16B aligned)
#define OFF_BUFT 0        // 20 chunks = 51200
#define OFF_BUFA 51200    // 16 chunks = 40960
#define OFF_BUFH 92160    // 8 chunks  = 20480
#define OFF_BIAS 112640   // 848 f32   = 3392
#define OFF_GRC  116032   // 800 f32   = 3200
#define OFF_WRC  119232   // 800 f32   = 3200
#define OFF_SC   122432   // 160 f32
#define OFF_MASK 123072   // 160 f32
#define OFF_MSUM 123712   // 8 f32
#define OFF_SSUM 123744   // 8 f32
#define SMEM_BYTES 123776

#define B_M1B0 0
#define B_M1B1 152
#define B_M2B0 256
#define B_M2B1 360
#define B_ATB0 416
#define B_ATB1 520
#define B_HPB0 624
#define B_HPB1 728
#define B_HPB2 832

// d_ws offsets in halves (bf16), each layer as wT[NR][KPAD]
#define WS_M1W0 0       // 160 x 32
#define WS_M1W1 5120    // 112 x 160
#define WS_M2W0 23040   // 112 x 128
#define WS_M2W1 37376   // 64  x 128
#define WS_ATW0 45568   // 112 x 128
#define WS_ATW1 59904   // 112 x 128
#define WS_HPW0 74240   // 112 x 64
#define WS_HPW1 81408   // 112 x 128
#define WS_HPW2 95744   // 16  x 128
#define WS_TOTAL 97792  // halves (195,584 B)

__device__ __forceinline__ short f2b(float f) {
    unsigned u = __builtin_bit_cast(unsigned, f);
    u += 0x7FFFu + ((u >> 16) & 1u);          // RNE
    return (short)(u >> 16);
}
__device__ __forceinline__ float b2f(short h) {
    unsigned u = ((unsigned)(unsigned short)h) << 16;
    return __builtin_bit_cast(float, u);
}

// ---- prologue: W[K][N] f32 -> wT[nl][k] bf16 in d_ws (zero padded)
__device__ __forceinline__ void stg(const float* __restrict__ W, int N,
                                    int KR, int KPAD, int NR, int Nsrc,
                                    short* dst, int gtid, int gsz) {
    int K8 = KPAD >> 3;
    for (int idx = gtid; idx < NR * K8; idx += gsz) {
        int k8 = idx / NR, nl = idx - k8 * NR;
        int k0 = k8 << 3;
        sx8 h;
        #pragma unroll
        for (int i = 0; i < 8; ++i) {
            int k = k0 + i;
            float v = (k < KR && nl < Nsrc) ? W[k * N + nl] : 0.f;
            h[i] = f2b(v);
        }
        *(sx8*)(dst + nl * KPAD + k0) = h;
    }
}

__global__ void stage_weights(
    const float* __restrict__ m1w0, const float* __restrict__ m1w1,
    const float* __restrict__ m2w0, const float* __restrict__ m2w1,
    const float* __restrict__ atw0, const float* __restrict__ atw1,
    const float* __restrict__ hpw0, const float* __restrict__ hpw1,
    const float* __restrict__ hpw2, short* __restrict__ ws)
{
    int gtid = blockIdx.x * blockDim.x + threadIdx.x;
    int gsz = gridDim.x * blockDim.x;
    stg(m1w0, 150, 13, 32, 160, 150, ws + WS_M1W0, gtid, gsz);
    stg(m1w1, 100, 150, 160, 112, 100, ws + WS_M1W1, gtid, gsz);
    stg(m2w0, 100, 100, 128, 112, 100, ws + WS_M2W0, gtid, gsz);
    stg(m2w1, 50, 100, 128, 64, 50, ws + WS_M2W1, gtid, gsz);
    stg(atw0, 100, 100, 128, 112, 100, ws + WS_ATW0, gtid, gsz);  // rows 0..99
    stg(atw1, 100, 100, 128, 112, 100, ws + WS_ATW1, gtid, gsz);
    stg(hpw0, 100, 50, 64, 112, 100, ws + WS_HPW0, gtid, gsz);    // rows 0..49
    stg(hpw1, 100, 100, 128, 112, 100, ws + WS_HPW1, gtid, gsz);
    stg(hpw2, 7, 100, 128, 16, 7, ws + WS_HPW2, gtid, gsz);
}

// ---- GEMM phase: B from LDS chunks, A from global frag layout.
// out[tok][n] = (relu)(init + sum_k act[tok][k] * W[k][n]); MS=5 -> MC=2.
template <int KT, bool RELU, bool UINIT>
__device__ __forceinline__ void gemm(const short* __restrict__ wg,
                                     const short* bIn, short* bOut,
                                     const float* initp, int initBstride,
                                     int Nt, int Nreal,
                                     int wave, int lm, int lq) {
    constexpr int KP = KT * 32;
    for (int tix = wave; tix < Nt * 5; tix += NW) {
        int nt = tix / 5, mh = tix - nt * 5;
        int n0l = nt * 16 + lq * 4;
        const short* ap = wg + (nt * 16 + lm) * KP + lq * 8;
        sx8 afr[KT];
        #pragma unroll
        for (int kt = 0; kt < KT; ++kt) afr[kt] = *(const sx8*)(ap + kt * 32);
        fx4 ib;
        if (UINIT) ib = *(const fx4*)(initp + n0l);
        #pragma unroll
        for (int mi = 0; mi < 2; ++mi) {
            int mt = mh * 2 + mi;
            int tok = mt * 16 + lm;
            fx4 acc;
            if (UINIT) acc = ib;
            else acc = *(const fx4*)(initp + (tok / 20) * initBstride + n0l);
            fx4 acc2 = {0.f, 0.f, 0.f, 0.f};
            const short* bp = bIn + tok * 8;
            #pragma unroll
            for (int kt = 0; kt < KT; ++kt) {
                sx8 b = *(const sx8*)(bp + (kt * 4 + lq) * CHH);
                if (kt & 1)
                    acc2 = __builtin_amdgcn_mfma_f32_16x16x32_bf16(afr[kt], b, acc2, 0, 0, 0);
                else
                    acc = __builtin_amdgcn_mfma_f32_16x16x32_bf16(afr[kt], b, acc, 0, 0, 0);
            }
            if (KT > 1) {
                acc[0] += acc2[0]; acc[1] += acc2[1];
                acc[2] += acc2[2]; acc[3] += acc2[3];
            }
            sx4 hv;
            #pragma unroll
            for (int r = 0; r < 4; ++r) {
                float v = acc[r];
                if (RELU) v = fmaxf(v, 0.f);
                if (n0l + r >= Nreal) v = 0.f;
                hv[r] = f2b(v);
            }
            *(sx4*)(bOut + (nt * 2 + (lq >> 1)) * CHH + tok * 8 + (lq & 1) * 4) = hv;
        }
    }
}

// zero chunks 14,15 of a buffer (cols 112..127)
__device__ __forceinline__ void zpad(short* buf, int tid) {
    for (int i = tid; i < 320; i += TB) {
        sx8 z = {0, 0, 0, 0, 0, 0, 0, 0};
        *(sx8*)(buf + 14 * CHH + i * 8) = z;
    }
}

__global__ __launch_bounds__(TB, 1) void sp_mfma_bf16(
    const float* __restrict__ state,
    const float* __restrict__ m1b0, const float* __restrict__ m1b1,
    const float* __restrict__ m2b0, const float* __restrict__ m2b1,
    const float* __restrict__ atw0, const float* __restrict__ atb0,
    const float* __restrict__ atb1,
    const float* __restrict__ atw2, const float* __restrict__ atb2,
    const float* __restrict__ hpw0, const float* __restrict__ hpb0,
    const float* __restrict__ hpb1, const float* __restrict__ hpb2,
    const short* __restrict__ ws,
    float* __restrict__ out)
{
    __shared__ __align__(16) unsigned char smem[SMEM_BYTES];
    short* bufT  = (short*)(smem + OFF_BUFT);
    short* bufA  = (short*)(smem + OFF_BUFA);
    short* bufH2 = (short*)(smem + OFF_BUFH);
    float* biasv = (float*)(smem + OFF_BIAS);
    float* grc   = (float*)(smem + OFF_GRC);
    float* wrc   = (float*)(smem + OFF_WRC);
    float* scv   = (float*)(smem + OFF_SC);
    float* maskv = (float*)(smem + OFF_MASK);
    float* msum  = (float*)(smem + OFF_MSUM);
    float* ssum  = (float*)(smem + OFF_SSUM);

    const int tid  = threadIdx.x;
    const int lane = tid & 63;
    const int wave = tid >> 6;
    const int lm   = lane & 15;
    const int lq   = lane >> 4;
    const long gt0 = (long)blockIdx.x * MTOK;

    // ---- phase 1: biases, mask, x -> bufA chunks 0..3
    {
        const float* bs[9] = {m1b0, m1b1, m2b0, m2b1, atb0, atb1, hpb0, hpb1, hpb2};
        const int off[9] = {B_M1B0, B_M1B1, B_M2B0, B_M2B1, B_ATB0, B_ATB1, B_HPB0, B_HPB1, B_HPB2};
        const int sz[9]  = {150, 100, 100, 50, 100, 100, 100, 100, 7};
        const int pd[9]  = {152, 104, 104, 56, 104, 104, 104, 104, 16};
        #pragma unroll
        for (int r = 0; r < 9; ++r)
            for (int i = tid; i < pd[r]; i += TB)
                biasv[off[r] + i] = (i < sz[r]) ? bs[r][i] : 0.f;
        if (tid < MTOK) maskv[tid] = state[(gt0 + tid) * 14 + 13];
        for (int idx = tid; idx < MTOK * 4; idx += TB) {
            int row = idx >> 2, seg = idx & 3;
            const float* xp = state + (gt0 + row) * 14;
            sx8 h;
            #pragma unroll
            for (int i = 0; i < 8; ++i) {
                int k = seg * 8 + i;
                float v = (k < 13) ? xp[k] : 0.f;
                h[i] = f2b(v);
            }
            *(sx8*)(bufA + seg * CHH + row * 8) = h;
        }
    }
    __syncthreads();

    // ---- msum + m1L0 (13->150, relu): x(bufA) -> bufT
    if (tid < 8) {
        float s = 0.f;
        #pragma unroll
        for (int n = 0; n < 20; ++n) s += maskv[tid * 20 + n];
        msum[tid] = s;
    }
    gemm<1, true, true>(ws + WS_M1W0, bufA, bufT, biasv + B_M1B0, 0,
                        10, 150, wave, lm, lq);
    __syncthreads();

    // ---- m1L1 (150->100, relu): bufT -> bufA (h1)
    gemm<5, true, true>(ws + WS_M1W1, bufT, bufA, biasv + B_M1B1, 0,
                        7, 100, wave, lm, lq);
    zpad(bufA, tid);
    __syncthreads();

    // ---- glob[b][j] = (sum_n mask*h1)/msum -> grc
    for (int task = tid; task < 800; task += TB) {
        int b = task / 100, j = task - b * 100;
        float ms = msum[b];
        float inv = (ms > 0.f) ? 1.f / ms : 0.f;
        float a = 0.f;
        #pragma unroll
        for (int n = 0; n < 20; ++n)
            a = fmaf(maskv[b * 20 + n], b2f(bufA[(j >> 3) * CHH + (b * 20 + n) * 8 + (j & 7)]), a);
        grc[task] = a * inv;
    }
    __syncthreads();

    // ---- gcon = atb0 + glob @ atw0[100:200] (register-staged overwrite)
    {
        float g0 = 0.f;
        if (tid < 800) {
            int b = tid / 100, j = tid - b * 100;
            float a = biasv[B_ATB0 + j];
            #pragma unroll 10
            for (int k = 0; k < 100; ++k)
                a = fmaf(grc[b * 100 + k], atw0[(100 + k) * 100 + j], a);
            g0 = a;
        }
        __syncthreads();
        if (tid < 800) grc[tid] = g0;
    }
    __syncthreads();

    // ---- m2L0 (100->100, relu): h1(bufA) -> bufT (t2); zero bufT 14,15
    gemm<4, true, true>(ws + WS_M2W0, bufA, bufT, biasv + B_M2B0, 0,
                        7, 100, wave, lm, lq);
    zpad(bufT, tid);
    __syncthreads();

    // ---- m2L1 (100->50, no relu): bufT -> bufH2 (h2)
    gemm<4, false, true>(ws + WS_M2W1, bufT, bufH2, biasv + B_M2B1, 0,
                         4, 50, wave, lm, lq);
    __syncthreads();

    // ---- atL0 (100->100, relu, init=gcon): h1(bufA) -> bufT (ta)
    gemm<4, true, false>(ws + WS_ATW0, bufA, bufT, grc, 100,
                         7, 100, wave, lm, lq);
    __syncthreads();

    // ---- atL1 (100->100, relu): bufT -> bufA (ta2)
    gemm<4, true, true>(ws + WS_ATW1, bufT, bufA, biasv + B_ATB1, 0,
                        7, 100, wave, lm, lq);
    __syncthreads();

    // ---- scores + masked exp
    if (tid < MTOK) {
        float s = atb2[0];
        #pragma unroll
        for (int k8 = 0; k8 < 13; ++k8) {
            sx8 v = *(const sx8*)(bufA + k8 * CHH + tid * 8);
            #pragma unroll
            for (int i = 0; i < 8; ++i) {
                int k = k8 * 8 + i;
                if (k < 100) s = fmaf(b2f(v[i]), atw2[k], s);
            }
        }
        s *= maskv[tid];
        scv[tid] = (s != 0.f) ? __expf(s) : 0.f;
    }
    __syncthreads();
    if (tid < 8) {
        float s = 0.f;
        #pragma unroll
        for (int n = 0; n < 20; ++n) s += scv[tid * 20 + n];
        ssum[tid] = s;
    }
    __syncthreads();

    // ---- wsum[b][j] = sum_n (se/ssum)*h2 -> wrc[0,400)
    if (tid < 400) {
        int b = tid / 50, j = tid - b * 50;
        float ss = ssum[b];
        float inv = (ss > 0.f) ? 1.f / ss : 0.f;
        float a = 0.f;
        #pragma unroll
        for (int n = 0; n < 20; ++n)
            a = fmaf(scv[b * 20 + n], b2f(bufH2[(j >> 3) * CHH + (b * 20 + n) * 8 + (j & 7)]), a);
        wrc[b * 50 + j] = a * inv;
    }
    __syncthreads();

    // ---- hcon = hpb0 + wsum @ hpw0[50:100] (register-staged overwrite)
    {
        float g0 = 0.f;
        if (tid < 800) {
            int b = tid / 100, j = tid - b * 100;
            float a = biasv[B_HPB0 + j];
            #pragma unroll 10
            for (int k = 0; k < 50; ++k)
                a = fmaf(wrc[b * 50 + k], hpw0[(50 + k) * 100 + j], a);
            g0 = a;
        }
        __syncthreads();
        if (tid < 800) wrc[tid] = g0;
    }
    __syncthreads();

    // ---- hpL0 (50->100, relu, init=hcon): h2(bufH2) -> bufT (th)
    gemm<2, true, false>(ws + WS_HPW0, bufH2, bufT, wrc, 100,
                         7, 100, wave, lm, lq);
    __syncthreads();

    // ---- hpL1 (100->100, relu): bufT -> bufA (th2)
    gemm<4, true, true>(ws + WS_HPW1, bufT, bufA, biasv + B_HPB1, 0,
                        7, 100, wave, lm, lq);
    __syncthreads();

    // ---- hpL2 (100->7) -> global out
    for (int mt = wave; mt < 10; mt += NW) {
        int tok = mt * 16 + lm;
        fx4 acc = *(const fx4*)(biasv + B_HPB2 + lq * 4);
        fx4 acc2 = {0.f, 0.f, 0.f, 0.f};
        const short* ap = ws + WS_HPW2 + lm * 128 + lq * 8;
        const short* bp = bufA + tok * 8;
        #pragma unroll
        for (int kt = 0; kt < 4; ++kt) {
            sx8 a = *(const sx8*)(ap + kt * 32);
            sx8 b = *(const sx8*)(bp + (kt * 4 + lq) * CHH);
            if (kt & 1)
                acc2 = __builtin_amdgcn_mfma_f32_16x16x32_bf16(a, b, acc2, 0, 0, 0);
            else
                acc = __builtin_amdgcn_mfma_f32_16x16x32_bf16(a, b, acc, 0, 0, 0);
        }
        acc[0] += acc2[0]; acc[1] += acc2[1]; acc[2] += acc2[2]; acc[3] += acc2[3];
        #pragma unroll
        for (int r = 0; r < 4; ++r) {
            int n = lq * 4 + r;
            if (n < 7) out[(gt0 + tok) * 7 + n] = acc[r];
        }
    }
}

extern "C" void kernel_launch(void* const* d_in, const int* in_sizes, int n_in,
                              void* d_out, int out_size, void* d_ws, size_t ws_size,
                              hipStream_t stream) {
    int si = 20, wb = 0;
    if (in_sizes[0] > 1000000) { si = 0; wb = 1; }
    const float* state = (const float*)d_in[si];
    const float* W[20];
    for (int i = 0; i < 20; ++i) W[i] = (const float*)d_in[wb + i];
    float* out = (float*)d_out;
    short* ws = (short*)d_ws;
    int Btot = in_sizes[si] / (20 * 14);
    int nblocks = Btot / 8;   // 8 b's (160 tokens) per block

    hipLaunchKernelGGL(stage_weights, dim3(48), dim3(256), 0, stream,
        W[0], W[2], W[4], W[6], W[8], W[10], W[14], W[16], W[18], ws);

    hipLaunchKernelGGL(sp_mfma_bf16, dim3(nblocks), dim3(TB), 0, stream,
        state,
        W[1], W[3],           // m1b0, m1b1
        W[5], W[7],           // m2b0, m2b1
        W[8], W[9],           // atw0 (for gcon glue), atb0
        W[11],                // atb1
        W[12], W[13],         // atw2, atb2
        W[14], W[15],         // hpw0 (for hcon glue), hpb0
        W[17], W[19],         // hpb1, hpb2
        ws, out);
}

// Round 7
// 514.000 us; speedup vs baseline: 1.4057x; 1.4057x over previous
//
#include <hip/hip_runtime.h>

// R7: bf16 MFMA, weights pre-staged in d_ws in CHUNK-OF-8 fragment layout
// wA[c][nl][8] (same pattern as B) -> a quad's A-load is 256B contiguous
// (coalesced), fixing R6's serial 16-line gathers. gemm restructured to
// 2x2 blocking: unit = (nt-pair, mt-pair); A-frags (2xKT) batch-loaded at
// unit start, B-frags loaded once per mt and REUSED across both nt
// (LDS B-traffic ~-45%); dual acc chains for MFMA ILP. NT templated so
// odd-N tails skip instead of duplicating. hpL2 A hoisted.
// Dataflow & numerics otherwise identical to R6 (passed, absmax 6.8e-3).

typedef short sx8 __attribute__((ext_vector_type(8)));
typedef short sx4 __attribute__((ext_vector_type(4)));
typedef float fx4 __attribute__((ext_vector_type(4)));

#define TB   1024
#define NW   16
#define MTOK 160
#define CHH  1280   // halves per k-chunk: 160 tok x 8

// LDS byte offsets (16B aligned)
#define OFF_BUFT 0        // 20 chunks = 51200
#define OFF_BUFA 51200    // 16 chunks = 40960
#define OFF_BUFH 92160    // 8 chunks  = 20480
#define OFF_BIAS 112640   // 848 f32   = 3392
#define OFF_GRC  116032   // 800 f32   = 3200
#define OFF_WRC  119232   // 800 f32   = 3200
#define OFF_SC   122432   // 160 f32
#define OFF_MASK 123072   // 160 f32
#define OFF_MSUM 123712   // 8 f32
#define OFF_SSUM 123744   // 8 f32
#define SMEM_BYTES 123776

#define B_M1B0 0
#define B_M1B1 152
#define B_M2B0 256
#define B_M2B1 360
#define B_ATB0 416
#define B_ATB1 520
#define B_HPB0 624
#define B_HPB1 728
#define B_HPB2 832

// d_ws offsets in halves (bf16), each layer as wA[c][nl][8], c in [0,KP/8)
#define WS_M1W0 0       // KP=32,  NR=160
#define WS_M1W1 5120    // KP=160, NR=112
#define WS_M2W0 23040   // KP=128, NR=112
#define WS_M2W1 37376   // KP=128, NR=64
#define WS_ATW0 45568   // KP=128, NR=112
#define WS_ATW1 59904   // KP=128, NR=112
#define WS_HPW0 74240   // KP=64,  NR=112
#define WS_HPW1 81408   // KP=128, NR=112
#define WS_HPW2 95744   // KP=128, NR=16

__device__ __forceinline__ short f2b(float f) {
    unsigned u = __builtin_bit_cast(unsigned, f);
    u += 0x7FFFu + ((u >> 16) & 1u);          // RNE
    return (short)(u >> 16);
}
__device__ __forceinline__ float b2f(short h) {
    unsigned u = ((unsigned)(unsigned short)h) << 16;
    return __builtin_bit_cast(float, u);
}

// ---- prologue: W[K][N] f32 -> wA[k8][nl][8] bf16 in d_ws (zero padded)
__device__ __forceinline__ void stg(const float* __restrict__ W, int N,
                                    int KR, int KPAD, int NR, int Nsrc,
                                    short* dst, int gtid, int gsz) {
    int K8 = KPAD >> 3;
    for (int idx = gtid; idx < NR * K8; idx += gsz) {
        int k8 = idx / NR, nl = idx - k8 * NR;
        int k0 = k8 << 3;
        sx8 h;
        #pragma unroll
        for (int i = 0; i < 8; ++i) {
            int k = k0 + i;
            float v = (k < KR && nl < Nsrc) ? W[k * N + nl] : 0.f;
            h[i] = f2b(v);
        }
        *(sx8*)(dst + (k8 * NR + nl) * 8) = h;
    }
}

__global__ void stage_weights(
    const float* __restrict__ m1w0, const float* __restrict__ m1w1,
    const float* __restrict__ m2w0, const float* __restrict__ m2w1,
    const float* __restrict__ atw0, const float* __restrict__ atw1,
    const float* __restrict__ hpw0, const float* __restrict__ hpw1,
    const float* __restrict__ hpw2, short* __restrict__ ws)
{
    int gtid = blockIdx.x * blockDim.x + threadIdx.x;
    int gsz = gridDim.x * blockDim.x;
    stg(m1w0, 150, 13, 32, 160, 150, ws + WS_M1W0, gtid, gsz);
    stg(m1w1, 100, 150, 160, 112, 100, ws + WS_M1W1, gtid, gsz);
    stg(m2w0, 100, 100, 128, 112, 100, ws + WS_M2W0, gtid, gsz);
    stg(m2w1, 50, 100, 128, 64, 50, ws + WS_M2W1, gtid, gsz);
    stg(atw0, 100, 100, 128, 112, 100, ws + WS_ATW0, gtid, gsz);  // rows 0..99
    stg(atw1, 100, 100, 128, 112, 100, ws + WS_ATW1, gtid, gsz);
    stg(hpw0, 100, 50, 64, 112, 100, ws + WS_HPW0, gtid, gsz);    // rows 0..49
    stg(hpw1, 100, 100, 128, 112, 100, ws + WS_HPW1, gtid, gsz);
    stg(hpw2, 7, 100, 128, 16, 7, ws + WS_HPW2, gtid, gsz);
}

// ---- GEMM phase, 2x2 blocked. Unit = (nt-pair, mt-pair).
// out[tok][n] = (relu)(init + sum_k act[tok][k] * W[k][n])
template <int KT, int NT, bool RELU, bool UINIT>
__device__ __forceinline__ void gemm(const short* __restrict__ wg, int NR,
                                     const short* bIn, short* bOut,
                                     const float* initp, int initBstride,
                                     int Nreal, int wave, int lm, int lq) {
    constexpr int NG = (NT + 1) / 2;
    for (int u = wave; u < NG * 5; u += NW) {
        int ng = u / 5, mg = u - ng * 5;
        int nt0 = ng * 2, nt1 = nt0 + 1;
        bool hasN1 = !((NT & 1) && (ng == NG - 1));
        sx8 a0[KT], a1[KT];
        #pragma unroll
        for (int kt = 0; kt < KT; ++kt)
            a0[kt] = *(const sx8*)(wg + ((kt * 4 + lq) * NR + nt0 * 16 + lm) * 8);
        if (hasN1) {
            #pragma unroll
            for (int kt = 0; kt < KT; ++kt)
                a1[kt] = *(const sx8*)(wg + ((kt * 4 + lq) * NR + nt1 * 16 + lm) * 8);
        }
        int n0l0 = nt0 * 16 + lq * 4;
        int n0l1 = nt1 * 16 + lq * 4;
        fx4 ib0, ib1;
        if (UINIT) {
            ib0 = *(const fx4*)(initp + n0l0);
            if (hasN1) ib1 = *(const fx4*)(initp + n0l1);
        }
        #pragma unroll
        for (int mi = 0; mi < 2; ++mi) {
            int mt = mg * 2 + mi;
            int tok = mt * 16 + lm;
            sx8 bfr[KT];
            #pragma unroll
            for (int kt = 0; kt < KT; ++kt)
                bfr[kt] = *(const sx8*)(bIn + (kt * 4 + lq) * CHH + tok * 8);
            fx4 acc0, acc1;
            if (UINIT) acc0 = ib0;
            else acc0 = *(const fx4*)(initp + (tok / 20) * initBstride + n0l0);
            if (hasN1) {
                if (UINIT) acc1 = ib1;
                else acc1 = *(const fx4*)(initp + (tok / 20) * initBstride + n0l1);
            }
            #pragma unroll
            for (int kt = 0; kt < KT; ++kt) {
                acc0 = __builtin_amdgcn_mfma_f32_16x16x32_bf16(a0[kt], bfr[kt], acc0, 0, 0, 0);
                if (hasN1)
                    acc1 = __builtin_amdgcn_mfma_f32_16x16x32_bf16(a1[kt], bfr[kt], acc1, 0, 0, 0);
            }
            sx4 hv;
            #pragma unroll
            for (int r = 0; r < 4; ++r) {
                float v = acc0[r];
                if (RELU) v = fmaxf(v, 0.f);
                if (n0l0 + r >= Nreal) v = 0.f;
                hv[r] = f2b(v);
            }
            *(sx4*)(bOut + (nt0 * 2 + (lq >> 1)) * CHH + tok * 8 + (lq & 1) * 4) = hv;
            if (hasN1) {
                #pragma unroll
                for (int r = 0; r < 4; ++r) {
                    float v = acc1[r];
                    if (RELU) v = fmaxf(v, 0.f);
                    if (n0l1 + r >= Nreal) v = 0.f;
                    hv[r] = f2b(v);
                }
                *(sx4*)(bOut + (nt1 * 2 + (lq >> 1)) * CHH + tok * 8 + (lq & 1) * 4) = hv;
            }
        }
    }
}

// zero chunks 14,15 of a buffer (cols 112..127)
__device__ __forceinline__ void zpad(short* buf, int tid) {
    for (int i = tid; i < 320; i += TB) {
        sx8 z = {0, 0, 0, 0, 0, 0, 0, 0};
        *(sx8*)(buf + 14 * CHH + i * 8) = z;
    }
}

__global__ __launch_bounds__(TB, 4) void sp_mfma_bf16(
    const float* __restrict__ state,
    const float* __restrict__ m1b0, const float* __restrict__ m1b1,
    const float* __restrict__ m2b0, const float* __restrict__ m2b1,
    const float* __restrict__ atw0, const float* __restrict__ atb0,
    const float* __restrict__ atb1,
    const float* __restrict__ atw2, const float* __restrict__ atb2,
    const float* __restrict__ hpw0, const float* __restrict__ hpb0,
    const float* __restrict__ hpb1, const float* __restrict__ hpb2,
    const short* __restrict__ ws,
    float* __restrict__ out)
{
    __shared__ __align__(16) unsigned char smem[SMEM_BYTES];
    short* bufT  = (short*)(smem + OFF_BUFT);
    short* bufA  = (short*)(smem + OFF_BUFA);
    short* bufH2 = (short*)(smem + OFF_BUFH);
    float* biasv = (float*)(smem + OFF_BIAS);
    float* grc   = (float*)(smem + OFF_GRC);
    float* wrc   = (float*)(smem + OFF_WRC);
    float* scv   = (float*)(smem + OFF_SC);
    float* maskv = (float*)(smem + OFF_MASK);
    float* msum  = (float*)(smem + OFF_MSUM);
    float* ssum  = (float*)(smem + OFF_SSUM);

    const int tid  = threadIdx.x;
    const int lane = tid & 63;
    const int wave = tid >> 6;
    const int lm   = lane & 15;
    const int lq   = lane >> 4;
    const long gt0 = (long)blockIdx.x * MTOK;

    // ---- phase 1: biases, mask, x -> bufA chunks 0..3
    {
        const float* bs[9] = {m1b0, m1b1, m2b0, m2b1, atb0, atb1, hpb0, hpb1, hpb2};
        const int off[9] = {B_M1B0, B_M1B1, B_M2B0, B_M2B1, B_ATB0, B_ATB1, B_HPB0, B_HPB1, B_HPB2};
        const int sz[9]  = {150, 100, 100, 50, 100, 100, 100, 100, 7};
        const int pd[9]  = {152, 104, 104, 56, 104, 104, 104, 104, 16};
        #pragma unroll
        for (int r = 0; r < 9; ++r)
            for (int i = tid; i < pd[r]; i += TB)
                biasv[off[r] + i] = (i < sz[r]) ? bs[r][i] : 0.f;
        if (tid < MTOK) maskv[tid] = state[(gt0 + tid) * 14 + 13];
        for (int idx = tid; idx < MTOK * 4; idx += TB) {
            int row = idx >> 2, seg = idx & 3;
            const float* xp = state + (gt0 + row) * 14;
            sx8 h;
            #pragma unroll
            for (int i = 0; i < 8; ++i) {
                int k = seg * 8 + i;
                float v = (k < 13) ? xp[k] : 0.f;
                h[i] = f2b(v);
            }
            *(sx8*)(bufA + seg * CHH + row * 8) = h;
        }
    }
    __syncthreads();

    // ---- msum + m1L0 (13->150, relu): x(bufA) -> bufT
    if (tid < 8) {
        float s = 0.f;
        #pragma unroll
        for (int n = 0; n < 20; ++n) s += maskv[tid * 20 + n];
        msum[tid] = s;
    }
    gemm<1, 10, true, true>(ws + WS_M1W0, 160, bufA, bufT, biasv + B_M1B0, 0,
                            150, wave, lm, lq);
    __syncthreads();

    // ---- m1L1 (150->100, relu): bufT -> bufA (h1)
    gemm<5, 7, true, true>(ws + WS_M1W1, 112, bufT, bufA, biasv + B_M1B1, 0,
                           100, wave, lm, lq);
    zpad(bufA, tid);
    __syncthreads();

    // ---- glob[b][j] = (sum_n mask*h1)/msum -> grc
    for (int task = tid; task < 800; task += TB) {
        int b = task / 100, j = task - b * 100;
        float ms = msum[b];
        float inv = (ms > 0.f) ? 1.f / ms : 0.f;
        float a = 0.f;
        #pragma unroll
        for (int n = 0; n < 20; ++n)
            a = fmaf(maskv[b * 20 + n], b2f(bufA[(j >> 3) * CHH + (b * 20 + n) * 8 + (j & 7)]), a);
        grc[task] = a * inv;
    }
    __syncthreads();

    // ---- gcon = atb0 + glob @ atw0[100:200] (register-staged overwrite)
    {
        float g0 = 0.f;
        if (tid < 800) {
            int b = tid / 100, j = tid - b * 100;
            float a = biasv[B_ATB0 + j];
            #pragma unroll 10
            for (int k = 0; k < 100; ++k)
                a = fmaf(grc[b * 100 + k], atw0[(100 + k) * 100 + j], a);
            g0 = a;
        }
        __syncthreads();
        if (tid < 800) grc[tid] = g0;
    }
    __syncthreads();

    // ---- m2L0 (100->100, relu): h1(bufA) -> bufT (t2); zero bufT 14,15
    gemm<4, 7, true, true>(ws + WS_M2W0, 112, bufA, bufT, biasv + B_M2B0, 0,
                           100, wave, lm, lq);
    zpad(bufT, tid);
    __syncthreads();

    // ---- m2L1 (100->50, no relu): bufT -> bufH2 (h2)
    gemm<4, 4, false, true>(ws + WS_M2W1, 64, bufT, bufH2, biasv + B_M2B1, 0,
                            50, wave, lm, lq);
    __syncthreads();

    // ---- atL0 (100->100, relu, init=gcon): h1(bufA) -> bufT (ta)
    gemm<4, 7, true, false>(ws + WS_ATW0, 112, bufA, bufT, grc, 100,
                            100, wave, lm, lq);
    __syncthreads();

    // ---- atL1 (100->100, relu): bufT -> bufA (ta2)
    gemm<4, 7, true, true>(ws + WS_ATW1, 112, bufT, bufA, biasv + B_ATB1, 0,
                           100, wave, lm, lq);
    __syncthreads();

    // ---- scores + masked exp
    if (tid < MTOK) {
        float s = atb2[0];
        #pragma unroll
        for (int k8 = 0; k8 < 13; ++k8) {
            sx8 v = *(const sx8*)(bufA + k8 * CHH + tid * 8);
            #pragma unroll
            for (int i = 0; i < 8; ++i) {
                int k = k8 * 8 + i;
                if (k < 100) s = fmaf(b2f(v[i]), atw2[k], s);
            }
        }
        s *= maskv[tid];
        scv[tid] = (s != 0.f) ? __expf(s) : 0.f;
    }
    __syncthreads();
    if (tid < 8) {
        float s = 0.f;
        #pragma unroll
        for (int n = 0; n < 20; ++n) s += scv[tid * 20 + n];
        ssum[tid] = s;
    }
    __syncthreads();

    // ---- wsum[b][j] = sum_n (se/ssum)*h2 -> wrc[0,400)
    if (tid < 400) {
        int b = tid / 50, j = tid - b * 50;
        float ss = ssum[b];
        float inv = (ss > 0.f) ? 1.f / ss : 0.f;
        float a = 0.f;
        #pragma unroll
        for (int n = 0; n < 20; ++n)
            a = fmaf(scv[b * 20 + n], b2f(bufH2[(j >> 3) * CHH + (b * 20 + n) * 8 + (j & 7)]), a);
        wrc[b * 50 + j] = a * inv;
    }
    __syncthreads();

    // ---- hcon = hpb0 + wsum @ hpw0[50:100] (register-staged overwrite)
    {
        float g0 = 0.f;
        if (tid < 800) {
            int b = tid / 100, j = tid - b * 100;
            float a = biasv[B_HPB0 + j];
            #pragma unroll 10
            for (int k = 0; k < 50; ++k)
                a = fmaf(wrc[b * 50 + k], hpw0[(50 + k) * 100 + j], a);
            g0 = a;
        }
        __syncthreads();
        if (tid < 800) wrc[tid] = g0;
    }
    __syncthreads();

    // ---- hpL0 (50->100, relu, init=hcon): h2(bufH2) -> bufT (th)
    gemm<2, 7, true, false>(ws + WS_HPW0, 112, bufH2, bufT, wrc, 100,
                            100, wave, lm, lq);
    __syncthreads();

    // ---- hpL1 (100->100, relu): bufT -> bufA (th2)
    gemm<4, 7, true, true>(ws + WS_HPW1, 112, bufT, bufA, biasv + B_HPB1, 0,
                           100, wave, lm, lq);
    __syncthreads();

    // ---- hpL2 (100->7) -> global out; A-frags hoisted (shared by all mt)
    {
        sx8 afr[4];
        #pragma unroll
        for (int kt = 0; kt < 4; ++kt)
            afr[kt] = *(const sx8*)(ws + WS_HPW2 + ((kt * 4 + lq) * 16 + lm) * 8);
        fx4 ib = *(const fx4*)(biasv + B_HPB2 + lq * 4);
        for (int mt = wave; mt < 10; mt += NW) {
            int tok = mt * 16 + lm;
            fx4 acc = ib;
            const short* bp = bufA + tok * 8;
            #pragma unroll
            for (int kt = 0; kt < 4; ++kt) {
                sx8 b = *(const sx8*)(bp + (kt * 4 + lq) * CHH);
                acc = __builtin_amdgcn_mfma_f32_16x16x32_bf16(afr[kt], b, acc, 0, 0, 0);
            }
            #pragma unroll
            for (int r = 0; r < 4; ++r) {
                int n = lq * 4 + r;
                if (n < 7) out[(gt0 + tok) * 7 + n] = acc[r];
            }
        }
    }
}

extern "C" void kernel_launch(void* const* d_in, const int* in_sizes, int n_in,
                              void* d_out, int out_size, void* d_ws, size_t ws_size,
                              hipStream_t stream) {
    int si = 20, wb = 0;
    if (in_sizes[0] > 1000000) { si = 0; wb = 1; }
    const float* state = (const float*)d_in[si];
    const float* W[20];
    for (int i = 0; i < 20; ++i) W[i] = (const float*)d_in[wb + i];
    float* out = (float*)d_out;
    short* ws = (short*)d_ws;
    int Btot = in_sizes[si] / (20 * 14);
    int nblocks = Btot / 8;   // 8 b's (160 tokens) per block

    hipLaunchKernelGGL(stage_weights, dim3(128), dim3(256), 0, stream,
        W[0], W[2], W[4], W[6], W[8], W[10], W[14], W[16], W[18], ws);

    hipLaunchKernelGGL(sp_mfma_bf16, dim3(nblocks), dim3(TB), 0, stream,
        state,
        W[1], W[3],           // m1b0, m1b1
        W[5], W[7],           // m2b0, m2b1
        W[8], W[9],           // atw0 (for gcon glue), atb0
        W[11],                // atb1
        W[12], W[13],         // atw2, atb2
        W[14], W[15],         // hpw0 (for hcon glue), hpb0
        W[17], W[19],         // hpb1, hpb2
        ws, out);
}

// Round 8
// 453.341 us; speedup vs baseline: 1.5938x; 1.1338x over previous
//
#include <hip/hip_runtime.h>

// R8: two structural changes on the verified R7 dataflow:
//  (a) NB=4 batch elems / 80 tokens / TB=512 / LDS 67.7KB -> 2 blocks
//      co-resident per CU (same 16 waves/CU): one block's barrier drains are
//      hidden by the other block's waves.
//  (b) gcon/hcon glue (120k chained lane-FMAs + ~1900 scattered global-f32
//      loads per block) replaced by tiny MFMA passes: atw0[100:200] and
//      hpw0[50:100] pre-staged in d_ws; glob/wsum staged bf16 into a
//      16-token chunk buffer (bufG); D written f32 straight to grc/wrc.
// Everything else (layouts, epilogues, reductions) identical to R7.

typedef short sx8 __attribute__((ext_vector_type(8)));
typedef short sx4 __attribute__((ext_vector_type(4)));
typedef float fx4 __attribute__((ext_vector_type(4)));

#define TB   512
#define NW   8
#define NB   4      // batch elems per block
#define MTOK 80     // NB*20 tokens
#define MT   5      // m-tiles of 16
#define CHH  640    // halves per k-chunk: MTOK x 8
#define CHG  128    // halves per bufG chunk: 16 tok x 8

// LDS byte offsets (16B aligned)
#define OFF_BUFT 0        // 20 chunks x 1280B = 25600
#define OFF_BUFA 25600    // 16 chunks = 20480
#define OFF_BUFH 46080    // 8 chunks  = 10240
#define OFF_BUFG 56320    // 16 chunks x 256B = 4096
#define OFF_BIAS 60416    // 848 f32 = 3392
#define OFF_GRC  63808    // 400 f32 = 1600
#define OFF_WRC  65408    // 400 f32 = 1600
#define OFF_SC   67008    // 80 f32
#define OFF_MASK 67328    // 80 f32
#define OFF_MSUM 67648    // 4 f32 (pad 16)
#define OFF_SSUM 67664    // 4 f32 (pad 16)
#define SMEM_BYTES 67680  // -> 2 blocks/CU

#define B_M1B0 0
#define B_M1B1 152
#define B_M2B0 256
#define B_M2B1 360
#define B_ATB0 416
#define B_ATB1 520
#define B_HPB0 624
#define B_HPB1 728
#define B_HPB2 832

// d_ws offsets in halves; each layer as wA[k8][nl][8]
#define WS_M1W0  0        // KP=32,  NR=160
#define WS_M1W1  5120     // KP=160, NR=112
#define WS_M2W0  23040    // KP=128, NR=112
#define WS_M2W1  37376    // KP=128, NR=64
#define WS_ATW0  45568    // KP=128, NR=112 (rows 0..99)
#define WS_ATW1  59904    // KP=128, NR=112
#define WS_HPW0  74240    // KP=64,  NR=112 (rows 0..49)
#define WS_HPW1  81408    // KP=128, NR=112
#define WS_HPW2  95744    // KP=128, NR=16
#define WS_ATW0H 97792    // KP=128, NR=112 (atw0 rows 100..199)
#define WS_HPW0H 112128   // KP=64,  NR=112 (hpw0 rows 50..99)

__device__ __forceinline__ short f2b(float f) {
    unsigned u = __builtin_bit_cast(unsigned, f);
    u += 0x7FFFu + ((u >> 16) & 1u);          // RNE
    return (short)(u >> 16);
}
__device__ __forceinline__ float b2f(short h) {
    unsigned u = ((unsigned)(unsigned short)h) << 16;
    return __builtin_bit_cast(float, u);
}

// ---- prologue: W[K][N] f32 -> wA[k8][nl][8] bf16 in d_ws (zero padded)
__device__ __forceinline__ void stg(const float* __restrict__ W, int N,
                                    int KR, int KPAD, int NR, int Nsrc,
                                    short* dst, int gtid, int gsz) {
    int K8 = KPAD >> 3;
    for (int idx = gtid; idx < NR * K8; idx += gsz) {
        int k8 = idx / NR, nl = idx - k8 * NR;
        int k0 = k8 << 3;
        sx8 h;
        #pragma unroll
        for (int i = 0; i < 8; ++i) {
            int k = k0 + i;
            float v = (k < KR && nl < Nsrc) ? W[k * N + nl] : 0.f;
            h[i] = f2b(v);
        }
        *(sx8*)(dst + (k8 * NR + nl) * 8) = h;
    }
}

__global__ void stage_weights(
    const float* __restrict__ m1w0, const float* __restrict__ m1w1,
    const float* __restrict__ m2w0, const float* __restrict__ m2w1,
    const float* __restrict__ atw0, const float* __restrict__ atw1,
    const float* __restrict__ hpw0, const float* __restrict__ hpw1,
    const float* __restrict__ hpw2, short* __restrict__ ws)
{
    int gtid = blockIdx.x * blockDim.x + threadIdx.x;
    int gsz = gridDim.x * blockDim.x;
    stg(m1w0, 150, 13, 32, 160, 150, ws + WS_M1W0, gtid, gsz);
    stg(m1w1, 100, 150, 160, 112, 100, ws + WS_M1W1, gtid, gsz);
    stg(m2w0, 100, 100, 128, 112, 100, ws + WS_M2W0, gtid, gsz);
    stg(m2w1, 50, 100, 128, 64, 50, ws + WS_M2W1, gtid, gsz);
    stg(atw0, 100, 100, 128, 112, 100, ws + WS_ATW0, gtid, gsz);
    stg(atw1, 100, 100, 128, 112, 100, ws + WS_ATW1, gtid, gsz);
    stg(hpw0, 100, 50, 64, 112, 100, ws + WS_HPW0, gtid, gsz);
    stg(hpw1, 100, 100, 128, 112, 100, ws + WS_HPW1, gtid, gsz);
    stg(hpw2, 7, 100, 128, 16, 7, ws + WS_HPW2, gtid, gsz);
    stg(atw0 + 100 * 100, 100, 100, 128, 112, 100, ws + WS_ATW0H, gtid, gsz);
    stg(hpw0 + 50 * 100, 100, 50, 64, 112, 100, ws + WS_HPW0H, gtid, gsz);
}

// ---- main GEMM: 2-nt x (mt-pair w/ odd tail). B reused across both nt.
template <int KT, int NT, bool RELU, bool UINIT>
__device__ __forceinline__ void gemm(const short* __restrict__ wg, int NR,
                                     const short* bIn, short* bOut,
                                     const float* initp, int initBstride,
                                     int Nreal, int wave, int lm, int lq) {
    constexpr int NG = (NT + 1) / 2;
    for (int u = wave; u < NG * 3; u += NW) {
        int ng = u / 3, mg = u - ng * 3;
        int nt0 = ng * 2, nt1 = nt0 + 1;
        bool hasN1 = !((NT & 1) && (ng == NG - 1));
        sx8 a0[KT], a1[KT];
        #pragma unroll
        for (int kt = 0; kt < KT; ++kt)
            a0[kt] = *(const sx8*)(wg + ((kt * 4 + lq) * NR + nt0 * 16 + lm) * 8);
        if (hasN1) {
            #pragma unroll
            for (int kt = 0; kt < KT; ++kt)
                a1[kt] = *(const sx8*)(wg + ((kt * 4 + lq) * NR + nt1 * 16 + lm) * 8);
        }
        int n0l0 = nt0 * 16 + lq * 4;
        int n0l1 = nt1 * 16 + lq * 4;
        fx4 ib0, ib1;
        if (UINIT) {
            ib0 = *(const fx4*)(initp + n0l0);
            if (hasN1) ib1 = *(const fx4*)(initp + n0l1);
        }
        int mcount = (mg == 2) ? 1 : 2;   // MT=5 tail
        #pragma unroll 2
        for (int mi = 0; mi < mcount; ++mi) {
            int mt = mg * 2 + mi;
            int tok = mt * 16 + lm;
            sx8 bfr[KT];
            #pragma unroll
            for (int kt = 0; kt < KT; ++kt)
                bfr[kt] = *(const sx8*)(bIn + (kt * 4 + lq) * CHH + tok * 8);
            fx4 acc0, acc1;
            if (UINIT) acc0 = ib0;
            else acc0 = *(const fx4*)(initp + (tok / 20) * initBstride + n0l0);
            if (hasN1) {
                if (UINIT) acc1 = ib1;
                else acc1 = *(const fx4*)(initp + (tok / 20) * initBstride + n0l1);
            }
            #pragma unroll
            for (int kt = 0; kt < KT; ++kt) {
                acc0 = __builtin_amdgcn_mfma_f32_16x16x32_bf16(a0[kt], bfr[kt], acc0, 0, 0, 0);
                if (hasN1)
                    acc1 = __builtin_amdgcn_mfma_f32_16x16x32_bf16(a1[kt], bfr[kt], acc1, 0, 0, 0);
            }
            sx4 hv;
            #pragma unroll
            for (int r = 0; r < 4; ++r) {
                float v = acc0[r];
                if (RELU) v = fmaxf(v, 0.f);
                if (n0l0 + r >= Nreal) v = 0.f;
                hv[r] = f2b(v);
            }
            *(sx4*)(bOut + (nt0 * 2 + (lq >> 1)) * CHH + tok * 8 + (lq & 1) * 4) = hv;
            if (hasN1) {
                #pragma unroll
                for (int r = 0; r < 4; ++r) {
                    float v = acc1[r];
                    if (RELU) v = fmaxf(v, 0.f);
                    if (n0l1 + r >= Nreal) v = 0.f;
                    hv[r] = f2b(v);
                }
                *(sx4*)(bOut + (nt1 * 2 + (lq >> 1)) * CHH + tok * 8 + (lq & 1) * 4) = hv;
            }
        }
    }
}

// ---- reduction GEMM (gcon/hcon): M=16 single tile from bufG, f32 out.
// outF[b*100+n] = bias[n] + sum_k bufG[b][k] * W[k][n], b = lane row < NB.
template <int KT, int NT>
__device__ __forceinline__ void gemmR(const short* __restrict__ wg, int NR,
                                      const short* bG, float* outF,
                                      const float* biasp,
                                      int wave, int lm, int lq) {
    constexpr int NG = (NT + 1) / 2;
    for (int u = wave; u < NG; u += NW) {
        int nt0 = u * 2, nt1 = nt0 + 1;
        bool hasN1 = !((NT & 1) && (u == NG - 1));
        sx8 a0[KT], a1[KT], bfr[KT];
        #pragma unroll
        for (int kt = 0; kt < KT; ++kt) {
            a0[kt] = *(const sx8*)(wg + ((kt * 4 + lq) * NR + nt0 * 16 + lm) * 8);
            bfr[kt] = *(const sx8*)(bG + (kt * 4 + lq) * CHG + lm * 8);
        }
        if (hasN1) {
            #pragma unroll
            for (int kt = 0; kt < KT; ++kt)
                a1[kt] = *(const sx8*)(wg + ((kt * 4 + lq) * NR + nt1 * 16 + lm) * 8);
        }
        int n0l0 = nt0 * 16 + lq * 4;
        int n0l1 = nt1 * 16 + lq * 4;
        fx4 acc0 = *(const fx4*)(biasp + n0l0);
        fx4 acc1;
        if (hasN1) acc1 = *(const fx4*)(biasp + n0l1);
        #pragma unroll
        for (int kt = 0; kt < KT; ++kt) {
            acc0 = __builtin_amdgcn_mfma_f32_16x16x32_bf16(a0[kt], bfr[kt], acc0, 0, 0, 0);
            if (hasN1)
                acc1 = __builtin_amdgcn_mfma_f32_16x16x32_bf16(a1[kt], bfr[kt], acc1, 0, 0, 0);
        }
        if (lm < NB) {
            #pragma unroll
            for (int r = 0; r < 4; ++r) {
                int n = n0l0 + r;
                if (n < 100) outF[lm * 100 + n] = acc0[r];
            }
            if (hasN1) {
                #pragma unroll
                for (int r = 0; r < 4; ++r) {
                    int n = n0l1 + r;
                    if (n < 100) outF[lm * 100 + n] = acc1[r];
                }
            }
        }
    }
}

// zero chunks 14,15 of a 16-chunk activation buffer
__device__ __forceinline__ void zpad(short* buf, int tid) {
    for (int i = tid; i < 160; i += TB) {
        sx8 z = {0, 0, 0, 0, 0, 0, 0, 0};
        *(sx8*)(buf + 14 * CHH + i * 8) = z;
    }
}

__global__ __launch_bounds__(TB, 4) void sp_mfma_bf16(
    const float* __restrict__ state,
    const float* __restrict__ m1b0, const float* __restrict__ m1b1,
    const float* __restrict__ m2b0, const float* __restrict__ m2b1,
    const float* __restrict__ atb0, const float* __restrict__ atb1,
    const float* __restrict__ atw2, const float* __restrict__ atb2,
    const float* __restrict__ hpb0, const float* __restrict__ hpb1,
    const float* __restrict__ hpb2,
    const short* __restrict__ ws,
    float* __restrict__ out)
{
    __shared__ __align__(16) unsigned char smem[SMEM_BYTES];
    short* bufT  = (short*)(smem + OFF_BUFT);
    short* bufA  = (short*)(smem + OFF_BUFA);
    short* bufH2 = (short*)(smem + OFF_BUFH);
    short* bufG  = (short*)(smem + OFF_BUFG);
    float* biasv = (float*)(smem + OFF_BIAS);
    float* grc   = (float*)(smem + OFF_GRC);
    float* wrc   = (float*)(smem + OFF_WRC);
    float* scv   = (float*)(smem + OFF_SC);
    float* maskv = (float*)(smem + OFF_MASK);
    float* msum  = (float*)(smem + OFF_MSUM);
    float* ssum  = (float*)(smem + OFF_SSUM);

    const int tid  = threadIdx.x;
    const int lane = tid & 63;
    const int wave = tid >> 6;
    const int lm   = lane & 15;
    const int lq   = lane >> 4;
    const long gt0 = (long)blockIdx.x * MTOK;

    // ---- phase 1: biases, mask, x -> bufA chunks 0..3
    {
        const float* bs[9] = {m1b0, m1b1, m2b0, m2b1, atb0, atb1, hpb0, hpb1, hpb2};
        const int off[9] = {B_M1B0, B_M1B1, B_M2B0, B_M2B1, B_ATB0, B_ATB1, B_HPB0, B_HPB1, B_HPB2};
        const int sz[9]  = {150, 100, 100, 50, 100, 100, 100, 100, 7};
        const int pd[9]  = {152, 104, 104, 56, 104, 104, 104, 104, 16};
        #pragma unroll
        for (int r = 0; r < 9; ++r)
            for (int i = tid; i < pd[r]; i += TB)
                biasv[off[r] + i] = (i < sz[r]) ? bs[r][i] : 0.f;
        if (tid < MTOK) maskv[tid] = state[(gt0 + tid) * 14 + 13];
        for (int idx = tid; idx < MTOK * 4; idx += TB) {
            int row = idx >> 2, seg = idx & 3;
            const float* xp = state + (gt0 + row) * 14;
            sx8 h;
            #pragma unroll
            for (int i = 0; i < 8; ++i) {
                int k = seg * 8 + i;
                float v = (k < 13) ? xp[k] : 0.f;
                h[i] = f2b(v);
            }
            *(sx8*)(bufA + seg * CHH + row * 8) = h;
        }
    }
    __syncthreads();

    // ---- msum + m1L0 (13->150, relu): x(bufA) -> bufT
    if (tid < NB) {
        float s = 0.f;
        #pragma unroll
        for (int n = 0; n < 20; ++n) s += maskv[tid * 20 + n];
        msum[tid] = s;
    }
    gemm<1, 10, true, true>(ws + WS_M1W0, 160, bufA, bufT, biasv + B_M1B0, 0,
                            150, wave, lm, lq);
    __syncthreads();

    // ---- m1L1 (150->100, relu): bufT -> bufA (h1)
    gemm<5, 7, true, true>(ws + WS_M1W1, 112, bufT, bufA, biasv + B_M1B1, 0,
                           100, wave, lm, lq);
    zpad(bufA, tid);
    __syncthreads();

    // ---- glob -> bufG (bf16, full 2048-slot coverage incl. zero padding)
    for (int t = tid; t < 2048; t += TB) {
        int c = t >> 7, rem = t & 127;
        int tg = rem >> 3, h = rem & 7;
        int j = c * 8 + h;
        float v = 0.f;
        if (tg < NB && j < 100) {
            float ms = msum[tg];
            float inv = (ms > 0.f) ? 1.f / ms : 0.f;
            float a = 0.f;
            #pragma unroll
            for (int n = 0; n < 20; ++n)
                a = fmaf(maskv[tg * 20 + n],
                         b2f(bufA[(j >> 3) * CHH + (tg * 20 + n) * 8 + (j & 7)]), a);
            v = a * inv;
        }
        bufG[t] = f2b(v);
    }
    __syncthreads();

    // ---- gcon (MFMA): grc = atb0 + glob @ atw0[100:200]  [waves 0..3]
    //      + m2L0 (100->100, relu): h1(bufA) -> bufT (t2)   [all waves]
    gemmR<4, 7>(ws + WS_ATW0H, 112, bufG, grc, biasv + B_ATB0, wave, lm, lq);
    gemm<4, 7, true, true>(ws + WS_M2W0, 112, bufA, bufT, biasv + B_M2B0, 0,
                           100, wave, lm, lq);
    zpad(bufT, tid);
    __syncthreads();

    // ---- m2L1 (100->50, no relu): bufT -> bufH2 (h2)
    gemm<4, 4, false, true>(ws + WS_M2W1, 64, bufT, bufH2, biasv + B_M2B1, 0,
                            50, wave, lm, lq);
    __syncthreads();

    // ---- atL0 (100->100, relu, init=gcon): h1(bufA) -> bufT (ta)
    gemm<4, 7, true, false>(ws + WS_ATW0, 112, bufA, bufT, grc, 100,
                            100, wave, lm, lq);
    __syncthreads();

    // ---- atL1 (100->100, relu): bufT -> bufA (ta2)
    gemm<4, 7, true, true>(ws + WS_ATW1, 112, bufT, bufA, biasv + B_ATB1, 0,
                           100, wave, lm, lq);
    __syncthreads();

    // ---- scores + masked exp
    if (tid < MTOK) {
        float s = atb2[0];
        #pragma unroll
        for (int k8 = 0; k8 < 13; ++k8) {
            sx8 v = *(const sx8*)(bufA + k8 * CHH + tid * 8);
            #pragma unroll
            for (int i = 0; i < 8; ++i) {
                int k = k8 * 8 + i;
                if (k < 100) s = fmaf(b2f(v[i]), atw2[k], s);
            }
        }
        s *= maskv[tid];
        scv[tid] = (s != 0.f) ? __expf(s) : 0.f;
    }
    __syncthreads();
    if (tid < NB) {
        float s = 0.f;
        #pragma unroll
        for (int n = 0; n < 20; ++n) s += scv[tid * 20 + n];
        ssum[tid] = s;
    }
    __syncthreads();

    // ---- wsum -> bufG (bf16, chunks 0..7 full coverage)
    for (int t = tid; t < 1024; t += TB) {
        int c = t >> 7, rem = t & 127;
        int tg = rem >> 3, h = rem & 7;
        int j = c * 8 + h;
        float v = 0.f;
        if (tg < NB && j < 50) {
            float ss = ssum[tg];
            float inv = (ss > 0.f) ? 1.f / ss : 0.f;
            float a = 0.f;
            #pragma unroll
            for (int n = 0; n < 20; ++n)
                a = fmaf(scv[tg * 20 + n],
                         b2f(bufH2[(j >> 3) * CHH + (tg * 20 + n) * 8 + (j & 7)]), a);
            v = a * inv;
        }
        bufG[t] = f2b(v);
    }
    __syncthreads();

    // ---- hcon (MFMA): wrc = hpb0 + wsum @ hpw0[50:100]  [waves 0..3]
    gemmR<2, 7>(ws + WS_HPW0H, 112, bufG, wrc, biasv + B_HPB0, wave, lm, lq);
    __syncthreads();

    // ---- hpL0 (50->100, relu, init=hcon): h2(bufH2) -> bufT (th)
    gemm<2, 7, true, false>(ws + WS_HPW0, 112, bufH2, bufT, wrc, 100,
                            100, wave, lm, lq);
    __syncthreads();

    // ---- hpL1 (100->100, relu): bufT -> bufA (th2)
    gemm<4, 7, true, true>(ws + WS_HPW1, 112, bufT, bufA, biasv + B_HPB1, 0,
                           100, wave, lm, lq);
    __syncthreads();

    // ---- hpL2 (100->7) -> global out; A-frags hoisted
    {
        sx8 afr[4];
        #pragma unroll
        for (int kt = 0; kt < 4; ++kt)
            afr[kt] = *(const sx8*)(ws + WS_HPW2 + ((kt * 4 + lq) * 16 + lm) * 8);
        fx4 ib = *(const fx4*)(biasv + B_HPB2 + lq * 4);
        for (int mt = wave; mt < MT; mt += NW) {
            int tok = mt * 16 + lm;
            fx4 acc = ib;
            const short* bp = bufA + tok * 8;
            #pragma unroll
            for (int kt = 0; kt < 4; ++kt) {
                sx8 b = *(const sx8*)(bp + (kt * 4 + lq) * CHH);
                acc = __builtin_amdgcn_mfma_f32_16x16x32_bf16(afr[kt], b, acc, 0, 0, 0);
            }
            #pragma unroll
            for (int r = 0; r < 4; ++r) {
                int n = lq * 4 + r;
                if (n < 7) out[(gt0 + tok) * 7 + n] = acc[r];
            }
        }
    }
}

extern "C" void kernel_launch(void* const* d_in, const int* in_sizes, int n_in,
                              void* d_out, int out_size, void* d_ws, size_t ws_size,
                              hipStream_t stream) {
    int si = 20, wb = 0;
    if (in_sizes[0] > 1000000) { si = 0; wb = 1; }
    const float* state = (const float*)d_in[si];
    const float* W[20];
    for (int i = 0; i < 20; ++i) W[i] = (const float*)d_in[wb + i];
    float* out = (float*)d_out;
    short* ws = (short*)d_ws;
    int Btot = in_sizes[si] / (20 * 14);
    int nblocks = Btot / NB;   // 4 b's (80 tokens) per block -> 8192

    hipLaunchKernelGGL(stage_weights, dim3(128), dim3(256), 0, stream,
        W[0], W[2], W[4], W[6], W[8], W[10], W[14], W[16], W[18], ws);

    hipLaunchKernelGGL(sp_mfma_bf16, dim3(nblocks), dim3(TB), 0, stream,
        state,
        W[1], W[3],           // m1b0, m1b1
        W[5], W[7],           // m2b0, m2b1
        W[9], W[11],          // atb0, atb1
        W[12], W[13],         // atw2, atb2
        W[15], W[17], W[19],  // hpb0, hpb1, hpb2
        ws, out);
}